// Round 2
// baseline (304.695 us; speedup 1.0000x reference)
//
#include <hip/hip_runtime.h>
#include <math.h>

#define Bsz 8
#define Nn 1024
#define CIN 256
#define COUT 256
#define NR 4
#define NH 4

typedef unsigned short u16;
typedef __attribute__((ext_vector_type(8))) short bf16x8;
typedef __attribute__((ext_vector_type(4))) float f32x4;
typedef __attribute__((ext_vector_type(2))) float f32x2;

// ws layout (bytes):
//   fTf  : [sl=r*8+b][h][jb 0..31][nt 0..3][lane] bf16x8  16 MB @ 0
//   EEi  : [combo=r*4+h][b][n] float2 {e^li, e^(.2li)}    1 MB @ 16M
//   EEj  : [combo][b][n] float2 {e^lj, e^(.2lj)}          1 MB @ 17M
//   adjm : [b][i][r][16] u64                              4 MB @ 18M
//   Xbf  : [b*n][k] bf16                                  4 MB @ 22M
//   WbfT : [r][c][k] bf16                               512K @ 26M
//   wa_l : [combo][k] f32                                16K @ 26.5M
//   wa_r : [combo][k] f32                                16K @ +16K
#define OFF_EEI (16u << 20)
#define OFF_EEJ (17u << 20)
#define OFF_ADJM (18u << 20)
#define OFF_XBF (22u << 20)
#define OFF_WBFT (26u << 20)
#define OFF_WAL ((26u << 20) + (512u << 10))
#define OFF_WAR ((26u << 20) + (528u << 10))

#define LOG2E 1.4426950408889634f

__device__ __forceinline__ short f2bf(float x) {
  union { float f; unsigned u; } v; v.f = x;
  unsigned r = (v.u + 0x7FFFu + ((v.u >> 16) & 1u)) >> 16;
  return (short)r;
}

__device__ __forceinline__ float fast_exp2(float x) {
#if __has_builtin(__builtin_amdgcn_exp2f)
  return __builtin_amdgcn_exp2f(x);
#else
  return exp2f(x);
#endif
}

__device__ __forceinline__ int sbfe1(unsigned v, int bit) {
#if __has_builtin(__builtin_amdgcn_sbfe)
  return __builtin_amdgcn_sbfe((int)v, bit, 1);
#else
  return ((int)(v << (31 - bit))) >> 31;
#endif
}

__device__ __forceinline__ unsigned perm_hi16(unsigned hi, unsigned lo) {
#if __has_builtin(__builtin_amdgcn_perm)
  return __builtin_amdgcn_perm(hi, lo, 0x07060302u);
#else
  return (lo >> 16) | (hi & 0xFFFF0000u);
#endif
}

// async global->LDS, 16B per lane
__device__ __forceinline__ void gl_lds16(const void* g, void* l) {
  __builtin_amdgcn_global_load_lds(
      (const __attribute__((address_space(1))) unsigned int*)(unsigned long long)g,
      (__attribute__((address_space(3))) unsigned int*)(unsigned int)(unsigned long long)l,
      16, 0, 0);
}

// ---------- adjacency pack ----------
__global__ __launch_bounds__(256, 8)
void gatt_pack(const int4* __restrict__ adj4, unsigned long long* __restrict__ adjm) {
  const int t = threadIdx.x;
  const int wid = blockIdx.x * 4 + (t >> 6);
  const int lane = t & 63;
  const int jw = wid & 15;
  const int i = (wid >> 4) & 1023;
  const int b = wid >> 14;
  const int j = jw * 64 + lane;
  const int4 av = adj4[(size_t)(b * Nn + i) * Nn + j];
  const unsigned long long b0 = __ballot(av.x != 0);
  const unsigned long long b1 = __ballot(av.y != 0);
  const unsigned long long b2 = __ballot(av.z != 0);
  const unsigned long long b3 = __ballot(av.w != 0);
  if (lane < 4) {
    unsigned long long v = (lane == 0) ? b0 : (lane == 1) ? b1 : (lane == 2) ? b2 : b3;
    adjm[((size_t)((b * Nn + i) * NR + lane)) * 16 + jw] = v;
  }
}

// ---------- prep: W->bf16 transposed (bid<32) OR wa tables (bid>=32) ----------
__global__ __launch_bounds__(256, 4)
void gatt_prep(const float* __restrict__ W, const float* __restrict__ a,
               u16* __restrict__ WbfT, float* __restrict__ wa_l,
               float* __restrict__ wa_r) {
  const int t = threadIdx.x;
  if (blockIdx.x < 32) {
    const int r = blockIdx.x >> 3, kc = blockIdx.x & 7;
    u16 pk[32];
#pragma unroll 8
    for (int kk = 0; kk < 32; ++kk)
      pk[kk] = (u16)f2bf(W[(size_t)r * 65536 + (size_t)(kc * 32 + kk) * COUT + t]);
    u16* dst = WbfT + (size_t)r * 65536 + (size_t)t * CIN + kc * 32;
#pragma unroll
    for (int q = 0; q < 4; ++q) *(int4*)(dst + q * 8) = *(int4*)(pk + q * 8);
  } else {
    const int cb = blockIdx.x - 32;
    const int r = cb >> 2, h = cb & 3;
    float sl = 0.f, sr = 0.f;
    const float* Wp = W + (size_t)r * 65536 + (size_t)t * COUT + h * 64;
    const float* ap = a + r * 512 + h * 128;
#pragma unroll 8
    for (int c = 0; c < 64; ++c) {
      const float wv = Wp[c];
      sl = fmaf(wv, ap[c], sl);
      sr = fmaf(wv, ap[64 + c], sr);
    }
    wa_l[(size_t)cb * CIN + t] = sl;
    wa_r[(size_t)cb * CIN + t] = sr;
  }
}

// ---------- logits -> factored exp tables {e^l, e^(0.2 l)} + X->bf16 ----------
__global__ __launch_bounds__(256, 4)
void gatt_logitx(const float* __restrict__ X, const float4* __restrict__ wal4,
                 const float4* __restrict__ war4, float2* __restrict__ EEi,
                 float2* __restrict__ EEj, u16* __restrict__ Xbf) {
  __shared__ float Xs[16 * 260];
  const int t = threadIdx.x;
  const int row0 = blockIdx.x * 16;
  {
    const int il = t >> 4, kq = t & 15;
    const float4* xp = (const float4*)(X + (size_t)(row0 + il) * CIN + kq * 16);
    float4 v[4];
    u16 pk[16];
#pragma unroll
    for (int u = 0; u < 4; ++u) {
      v[u] = xp[u];
      pk[u * 4 + 0] = (u16)f2bf(v[u].x);
      pk[u * 4 + 1] = (u16)f2bf(v[u].y);
      pk[u * 4 + 2] = (u16)f2bf(v[u].z);
      pk[u * 4 + 3] = (u16)f2bf(v[u].w);
    }
    float4* dst = (float4*)(Xs + il * 260 + kq * 16);
#pragma unroll
    for (int u = 0; u < 4; ++u) dst[u] = v[u];
    u16* xb = Xbf + (size_t)(row0 + il) * CIN + kq * 16;
    *(int4*)xb = *(int4*)pk;
    *(int4*)(xb + 8) = *(int4*)(pk + 8);
  }
  __syncthreads();
  const int rl = t >> 4, combo = t & 15;
  float li = 0.f, lj = 0.f;
#pragma unroll 8
  for (int k4 = 0; k4 < 64; ++k4) {
    const float4 x4 = *(const float4*)(Xs + rl * 260 + k4 * 4);
    const float4 wl = wal4[combo * 64 + k4];
    const float4 wr = war4[combo * 64 + k4];
    li += x4.x * wl.x + x4.y * wl.y + x4.z * wl.z + x4.w * wl.w;
    lj += x4.x * wr.x + x4.y * wr.y + x4.z * wr.z + x4.w * wr.w;
  }
  const int g = row0 + rl, b = g >> 10, n = g & 1023;
  const size_t idx = ((size_t)(combo * Bsz + b)) * Nn + n;
  const float lis = li * LOG2E, ljs = lj * LOG2E;
  EEi[idx] = make_float2(fast_exp2(lis), fast_exp2(0.2f * lis));
  EEj[idx] = make_float2(fast_exp2(ljs), fast_exp2(0.2f * ljs));
}

// ---------- f GEMM via MFMA, frag-ordered output ----------
__global__ __launch_bounds__(256)
void gatt_fgemm(const u16* __restrict__ Xbf, const u16* __restrict__ WbfT,
                u16* __restrict__ fTf) {
  __shared__ u16 lds_w[8192];
  __shared__ u16 lds_x[2048];
  const int t = threadIdx.x;
  const int r = blockIdx.x & 3, b = (blockIdx.x >> 2) & 7, ntl = blockIdx.x >> 5;
  const int n0 = ntl * 64;
  const int g0 = b * Nn + n0;
  const int lane = t & 63, w = t >> 6;
  const int m = lane & 15, quad = lane >> 4;
  const int cw = w * 64;
  const int xq = quad ^ (m & 3);

  const u16* Wsrc = WbfT + (size_t)r * 65536;
  f32x4 acc[4][4];
#pragma unroll
  for (int ct = 0; ct < 4; ++ct)
#pragma unroll
    for (int nt = 0; nt < 4; ++nt) acc[ct][nt] = (f32x4){0.f, 0.f, 0.f, 0.f};

  for (int kc = 0; kc < 8; ++kc) {
    __syncthreads();
#pragma unroll
    for (int q = 0; q < 4; ++q) {
      const int s = q * 256 + t;
      const int c = s >> 2, ks = (s & 3) ^ (c & 3);
      gl_lds16(Wsrc + (size_t)c * CIN + kc * 32 + ks * 8, lds_w + s * 8);
    }
    {
      const int s = t;
      const int n = s >> 2, ks = (s & 3) ^ (n & 3);
      gl_lds16(Xbf + (size_t)(g0 + n) * CIN + kc * 32 + ks * 8, lds_x + s * 8);
    }
    __syncthreads();

    bf16x8 af[4], bfr[4];
#pragma unroll
    for (int ct = 0; ct < 4; ++ct)
      af[ct] = *(const bf16x8*)(lds_w + (cw + ct * 16 + m) * 32 + xq * 8);
#pragma unroll
    for (int nt = 0; nt < 4; ++nt)
      bfr[nt] = *(const bf16x8*)(lds_x + (nt * 16 + m) * 32 + xq * 8);
#pragma unroll
    for (int ct = 0; ct < 4; ++ct)
#pragma unroll
      for (int nt = 0; nt < 4; ++nt)
        acc[ct][nt] = __builtin_amdgcn_mfma_f32_16x16x32_bf16(af[ct], bfr[nt], acc[ct][nt], 0, 0, 0);
  }

  u16* fragbase = fTf + (size_t)(((r * Bsz + b) * 4 + w) * 128) * 512;
#pragma unroll
  for (int ct = 0; ct < 4; ++ct) {
#pragma unroll
    for (int ntf = 0; ntf < 4; ++ntf) {
      const int j = n0 + ntf * 16 + m;
      const int jb = j >> 5;
      const int qt = ((ntf & 1) << 1) | (m >> 3);
      const int e = m & 7;
      u16* dst = fragbase + (size_t)((jb * 4 + ct) * 512) + (qt * 16 + quad * 4) * 8 + e;
#pragma unroll
      for (int p = 0; p < 4; ++p) dst[p * 8] = (u16)f2bf(acc[ct][ntf][p]);
    }
  }
}

// ---------- attention: factored-exp (no transcendentals in loop), r fused ----------
// grid 256: bid&7 = b (pins b's fTf/adjm to one XCD L2); bid>>3 = itile (32 i).
// block 1024 = 16 waves = (r = w&3, h = w>>2).
// exp(leaky(li+lj)) = max(e^li*e^lj, e^.2li*e^.2lj): per pr = 2 pk_mul + 2 max
// + 2 and + 1 perm (no exp2, no add). EEj read via quad-uniform dwordx4 from
// global (L2-resident); no LDS staging phase. Epilogue: LDS r-reduction.
__global__ __launch_bounds__(1024, 4)
void gatt_attn(const unsigned long long* __restrict__ adjm,
               const u16* __restrict__ fTf, const float2* __restrict__ EEi,
               const float2* __restrict__ EEj, float* __restrict__ out) {
  __shared__ float smem[32 * 260];  // epilogue out-tile only

  const int t = threadIdx.x;
  const int b = blockIdx.x & 7;
  const int i0 = (blockIdx.x >> 3) * 32;
  const int w = t >> 6, lane = t & 63;
  const int r = w & 3, h = w >> 2;
  const int m = lane & 15, quad = lane >> 4;
  const int qo = quad * 8;
  const int combo = r * NH + h;

  const float2* EEib = EEi + ((size_t)(combo * Bsz + b)) * Nn;
  const float2 Li0 = EEib[i0 + m];
  const float2 Li1 = EEib[i0 + 16 + m];
  const f32x2 EI0 = {Li0.x, Li0.y};
  const f32x2 EI1 = {Li1.x, Li1.y};
  const float4* EEj4p = (const float4*)(EEj + ((size_t)(combo * Bsz + b)) * Nn);

  const unsigned long long* amp0 = adjm + ((size_t)((b * Nn + i0 + m) * NR + r)) * 16;
  const unsigned long long* amp1 = adjm + ((size_t)((b * Nn + i0 + 16 + m) * NR + r)) * 16;
  const bf16x8* fp = (const bf16x8*)fTf + (size_t)(((r * Bsz + b) * 4 + h)) * 8192;

  bf16x8 ones;
#pragma unroll
  for (int e = 0; e < 8; ++e) ones[e] = (short)0x3F80;

  f32x4 acc[2][4], den[2];
#pragma unroll
  for (int iw = 0; iw < 2; ++iw) {
    den[iw] = (f32x4){0.f, 0.f, 0.f, 0.f};
#pragma unroll
    for (int nt = 0; nt < 4; ++nt) acc[iw][nt] = (f32x4){0.f, 0.f, 0.f, 0.f};
  }

  for (int jq = 0; jq < 16; ++jq) {
    const uint2 mw0 = *(const uint2*)(amp0 + jq);
    const uint2 mw1 = *(const uint2*)(amp1 + jq);
#pragma unroll
    for (int half = 0; half < 2; ++half) {
      const int jb = jq * 2 + half;
      const unsigned mb0 = (half ? mw0.y : mw0.x) >> qo;
      const unsigned mb1 = (half ? mw1.y : mw1.x) >> qo;
      bf16x8 bfr[4];
#pragma unroll
      for (int nt = 0; nt < 4; ++nt) bfr[nt] = fp[(jb * 4 + nt) * 64 + lane];
      unsigned afu0[4], afu1[4];
#pragma unroll
      for (int pr = 0; pr < 4; ++pr) {
        const float4 v = EEj4p[jb * 16 + quad * 4 + pr];  // {Ej0,ej0,Ej1,ej1}
        const f32x2 v01 = {v.x, v.y};
        const f32x2 v23 = {v.z, v.w};
        {  // iw 0
          const f32x2 a0 = v01 * EI0;  // {Ei*Ej0, ei*ej0}
          const f32x2 a1 = v23 * EI0;
          const unsigned e0 =
              __float_as_uint(fmaxf(a0.x, a0.y)) & (unsigned)sbfe1(mb0, 2 * pr);
          const unsigned e1 =
              __float_as_uint(fmaxf(a1.x, a1.y)) & (unsigned)sbfe1(mb0, 2 * pr + 1);
          afu0[pr] = perm_hi16(e1, e0);
        }
        {  // iw 1
          const f32x2 a0 = v01 * EI1;
          const f32x2 a1 = v23 * EI1;
          const unsigned e0 =
              __float_as_uint(fmaxf(a0.x, a0.y)) & (unsigned)sbfe1(mb1, 2 * pr);
          const unsigned e1 =
              __float_as_uint(fmaxf(a1.x, a1.y)) & (unsigned)sbfe1(mb1, 2 * pr + 1);
          afu1[pr] = perm_hi16(e1, e0);
        }
      }
      union { unsigned u[4]; bf16x8 v; } af0, af1;
#pragma unroll
      for (int pr = 0; pr < 4; ++pr) { af0.u[pr] = afu0[pr]; af1.u[pr] = afu1[pr]; }
      den[0] = __builtin_amdgcn_mfma_f32_16x16x32_bf16(af0.v, ones, den[0], 0, 0, 0);
#pragma unroll
      for (int nt = 0; nt < 4; ++nt)
        acc[0][nt] = __builtin_amdgcn_mfma_f32_16x16x32_bf16(af0.v, bfr[nt], acc[0][nt], 0, 0, 0);
      den[1] = __builtin_amdgcn_mfma_f32_16x16x32_bf16(af1.v, ones, den[1], 0, 0, 0);
#pragma unroll
      for (int nt = 0; nt < 4; ++nt)
        acc[1][nt] = __builtin_amdgcn_mfma_f32_16x16x32_bf16(af1.v, bfr[nt], acc[1][nt], 0, 0, 0);
    }
  }

  // ---- epilogue: r-reduction in LDS ----
#define OSTRIDE 260
  __syncthreads();
#pragma unroll
  for (int rr = 0; rr < 4; ++rr) {
    if (r == rr) {
#pragma unroll
      for (int iw = 0; iw < 2; ++iw) {
#pragma unroll
        for (int p = 0; p < 4; ++p) {
          const float inv = __builtin_amdgcn_rcpf(den[iw][p]);
          float* op = smem + (iw * 16 + quad * 4 + p) * OSTRIDE + h * 64 + m;
#pragma unroll
          for (int nt = 0; nt < 4; ++nt) {
            const float v = acc[iw][nt][p] * inv;
            if (rr == 0) op[nt * 16] = v;
            else op[nt * 16] += v;
          }
        }
      }
    }
    __syncthreads();
  }

  // ---- coalesced store of the 32x256 f32 tile ----
#pragma unroll
  for (int q = 0; q < 2; ++q) {
    const int idx = q * 1024 + t;
    const int row = idx >> 6, c4 = idx & 63;
    const float4 v = *(const float4*)(smem + row * OSTRIDE + c4 * 4);
    ((float4*)out)[((size_t)(b * Nn + i0 + row)) * 64 + c4] = v;
  }
}

extern "C" void kernel_launch(void* const* d_in, const int* in_sizes, int n_in,
                              void* d_out, int out_size, void* d_ws, size_t ws_size,
                              hipStream_t stream) {
  const float* X = (const float*)d_in[0];
  const int4* adj4 = (const int4*)d_in[1];
  const float* W = (const float*)d_in[2];
  const float* a = (const float*)d_in[3];
  float* out = (float*)d_out;

  char* ws = (char*)d_ws;
  u16* fTf = (u16*)ws;
  float2* EEi = (float2*)(ws + OFF_EEI);
  float2* EEj = (float2*)(ws + OFF_EEJ);
  unsigned long long* adjm = (unsigned long long*)(ws + OFF_ADJM);
  u16* Xbf = (u16*)(ws + OFF_XBF);
  u16* WbfT = (u16*)(ws + OFF_WBFT);
  float* wa_l = (float*)(ws + OFF_WAL);
  float* wa_r = (float*)(ws + OFF_WAR);

  gatt_pack<<<dim3(32768), dim3(256), 0, stream>>>(adj4, adjm);
  gatt_prep<<<dim3(48), dim3(256), 0, stream>>>(W, a, WbfT, wa_l, wa_r);
  gatt_logitx<<<dim3(512), dim3(256), 0, stream>>>(X, (const float4*)wa_l,
                                                   (const float4*)wa_r, EEi, EEj, Xbf);
  gatt_fgemm<<<dim3(512), dim3(256), 0, stream>>>(Xbf, WbfT, fTf);
  gatt_attn<<<dim3(256), dim3(1024), 0, stream>>>(adjm, fTf, EEi, EEj, out);
}

// Round 4
// 289.059 us; speedup vs baseline: 1.0541x; 1.0541x over previous
//
#include <hip/hip_runtime.h>
#include <math.h>

#define Bsz 8
#define Nn 1024
#define CIN 256
#define COUT 256
#define NR 4
#define NH 4

typedef unsigned short u16;
typedef __attribute__((ext_vector_type(8))) short bf16x8;
typedef __attribute__((ext_vector_type(4))) float f32x4;
typedef __attribute__((ext_vector_type(2))) float f32x2;

// ws layout (bytes):
//   fTf  : [sl=r*8+b][h][jb 0..31][nt 0..3][lane] bf16x8  16 MB @ 0
//   EEi  : [combo=r*4+h][b][n] float2 {e^li, e^(.2li)}    1 MB @ 16M
//   EEj  : [combo][b][n] float2 {e^lj, e^(.2lj)}          1 MB @ 17M
//   adjm : [b][i][r][16] u64                              4 MB @ 18M
//   Xbf  : [b*n][k] bf16                                  4 MB @ 22M
//   WbfT : [r][c][k] bf16                               512K @ 26M
//   wa_l : [combo][k] f32                                16K @ 26.5M
//   wa_r : [combo][k] f32                                16K @ +16K
#define OFF_EEI (16u << 20)
#define OFF_EEJ (17u << 20)
#define OFF_ADJM (18u << 20)
#define OFF_XBF (22u << 20)
#define OFF_WBFT (26u << 20)
#define OFF_WAL ((26u << 20) + (512u << 10))
#define OFF_WAR ((26u << 20) + (528u << 10))

#define LOG2E 1.4426950408889634f

__device__ __forceinline__ short f2bf(float x) {
  union { float f; unsigned u; } v; v.f = x;
  unsigned r = (v.u + 0x7FFFu + ((v.u >> 16) & 1u)) >> 16;
  return (short)r;
}

__device__ __forceinline__ float fast_exp2(float x) {
#if __has_builtin(__builtin_amdgcn_exp2f)
  return __builtin_amdgcn_exp2f(x);
#else
  return exp2f(x);
#endif
}

__device__ __forceinline__ int sbfe1(unsigned v, int bit) {
#if __has_builtin(__builtin_amdgcn_sbfe)
  return __builtin_amdgcn_sbfe((int)v, bit, 1);
#else
  return ((int)(v << (31 - bit))) >> 31;
#endif
}

__device__ __forceinline__ unsigned perm_hi16(unsigned hi, unsigned lo) {
#if __has_builtin(__builtin_amdgcn_perm)
  return __builtin_amdgcn_perm(hi, lo, 0x07060302u);
#else
  return (lo >> 16) | (hi & 0xFFFF0000u);
#endif
}

// async global->LDS, 16B per lane
__device__ __forceinline__ void gl_lds16(const void* g, void* l) {
  __builtin_amdgcn_global_load_lds(
      (const __attribute__((address_space(1))) unsigned int*)(unsigned long long)g,
      (__attribute__((address_space(3))) unsigned int*)(unsigned int)(unsigned long long)l,
      16, 0, 0);
}

// ---------- adjacency pack ----------
__global__ __launch_bounds__(256, 8)
void gatt_pack(const int4* __restrict__ adj4, unsigned long long* __restrict__ adjm) {
  const int t = threadIdx.x;
  const int wid = blockIdx.x * 4 + (t >> 6);
  const int lane = t & 63;
  const int jw = wid & 15;
  const int i = (wid >> 4) & 1023;
  const int b = wid >> 14;
  const int j = jw * 64 + lane;
  const int4 av = adj4[(size_t)(b * Nn + i) * Nn + j];
  const unsigned long long b0 = __ballot(av.x != 0);
  const unsigned long long b1 = __ballot(av.y != 0);
  const unsigned long long b2 = __ballot(av.z != 0);
  const unsigned long long b3 = __ballot(av.w != 0);
  if (lane < 4) {
    unsigned long long v = (lane == 0) ? b0 : (lane == 1) ? b1 : (lane == 2) ? b2 : b3;
    adjm[((size_t)((b * Nn + i) * NR + lane)) * 16 + jw] = v;
  }
}

// ---------- prep: W->bf16 transposed (bid<32) OR wa tables (bid>=32) ----------
__global__ __launch_bounds__(256, 4)
void gatt_prep(const float* __restrict__ W, const float* __restrict__ a,
               u16* __restrict__ WbfT, float* __restrict__ wa_l,
               float* __restrict__ wa_r) {
  const int t = threadIdx.x;
  if (blockIdx.x < 32) {
    const int r = blockIdx.x >> 3, kc = blockIdx.x & 7;
    u16 pk[32];
#pragma unroll 8
    for (int kk = 0; kk < 32; ++kk)
      pk[kk] = (u16)f2bf(W[(size_t)r * 65536 + (size_t)(kc * 32 + kk) * COUT + t]);
    u16* dst = WbfT + (size_t)r * 65536 + (size_t)t * CIN + kc * 32;
#pragma unroll
    for (int q = 0; q < 4; ++q) *(int4*)(dst + q * 8) = *(int4*)(pk + q * 8);
  } else {
    const int cb = blockIdx.x - 32;
    const int r = cb >> 2, h = cb & 3;
    float sl = 0.f, sr = 0.f;
    const float* Wp = W + (size_t)r * 65536 + (size_t)t * COUT + h * 64;
    const float* ap = a + r * 512 + h * 128;
#pragma unroll 8
    for (int c = 0; c < 64; ++c) {
      const float wv = Wp[c];
      sl = fmaf(wv, ap[c], sl);
      sr = fmaf(wv, ap[64 + c], sr);
    }
    wa_l[(size_t)cb * CIN + t] = sl;
    wa_r[(size_t)cb * CIN + t] = sr;
  }
}

// ---------- logits -> factored exp tables {e^l, e^(0.2 l)} + X->bf16 ----------
__global__ __launch_bounds__(256, 4)
void gatt_logitx(const float* __restrict__ X, const float4* __restrict__ wal4,
                 const float4* __restrict__ war4, float2* __restrict__ EEi,
                 float2* __restrict__ EEj, u16* __restrict__ Xbf) {
  __shared__ float Xs[16 * 260];
  const int t = threadIdx.x;
  const int row0 = blockIdx.x * 16;
  {
    const int il = t >> 4, kq = t & 15;
    const float4* xp = (const float4*)(X + (size_t)(row0 + il) * CIN + kq * 16);
    float4 v[4];
    u16 pk[16];
#pragma unroll
    for (int u = 0; u < 4; ++u) {
      v[u] = xp[u];
      pk[u * 4 + 0] = (u16)f2bf(v[u].x);
      pk[u * 4 + 1] = (u16)f2bf(v[u].y);
      pk[u * 4 + 2] = (u16)f2bf(v[u].z);
      pk[u * 4 + 3] = (u16)f2bf(v[u].w);
    }
    float4* dst = (float4*)(Xs + il * 260 + kq * 16);
#pragma unroll
    for (int u = 0; u < 4; ++u) dst[u] = v[u];
    u16* xb = Xbf + (size_t)(row0 + il) * CIN + kq * 16;
    *(int4*)xb = *(int4*)pk;
    *(int4*)(xb + 8) = *(int4*)(pk + 8);
  }
  __syncthreads();
  const int rl = t >> 4, combo = t & 15;
  float li = 0.f, lj = 0.f;
#pragma unroll 8
  for (int k4 = 0; k4 < 64; ++k4) {
    const float4 x4 = *(const float4*)(Xs + rl * 260 + k4 * 4);
    const float4 wl = wal4[combo * 64 + k4];
    const float4 wr = war4[combo * 64 + k4];
    li += x4.x * wl.x + x4.y * wl.y + x4.z * wl.z + x4.w * wl.w;
    lj += x4.x * wr.x + x4.y * wr.y + x4.z * wr.z + x4.w * wr.w;
  }
  const int g = row0 + rl, b = g >> 10, n = g & 1023;
  const size_t idx = ((size_t)(combo * Bsz + b)) * Nn + n;
  const float lis = li * LOG2E, ljs = lj * LOG2E;
  EEi[idx] = make_float2(fast_exp2(lis), fast_exp2(0.2f * lis));
  EEj[idx] = make_float2(fast_exp2(ljs), fast_exp2(0.2f * ljs));
}

// ---------- f GEMM via MFMA, frag-ordered output ----------
__global__ __launch_bounds__(256)
void gatt_fgemm(const u16* __restrict__ Xbf, const u16* __restrict__ WbfT,
                u16* __restrict__ fTf) {
  __shared__ u16 lds_w[8192];
  __shared__ u16 lds_x[2048];
  const int t = threadIdx.x;
  const int r = blockIdx.x & 3, b = (blockIdx.x >> 2) & 7, ntl = blockIdx.x >> 5;
  const int n0 = ntl * 64;
  const int g0 = b * Nn + n0;
  const int lane = t & 63, w = t >> 6;
  const int m = lane & 15, quad = lane >> 4;
  const int cw = w * 64;
  const int xq = quad ^ (m & 3);

  const u16* Wsrc = WbfT + (size_t)r * 65536;
  f32x4 acc[4][4];
#pragma unroll
  for (int ct = 0; ct < 4; ++ct)
#pragma unroll
    for (int nt = 0; nt < 4; ++nt) acc[ct][nt] = (f32x4){0.f, 0.f, 0.f, 0.f};

  for (int kc = 0; kc < 8; ++kc) {
    __syncthreads();
#pragma unroll
    for (int q = 0; q < 4; ++q) {
      const int s = q * 256 + t;
      const int c = s >> 2, ks = (s & 3) ^ (c & 3);
      gl_lds16(Wsrc + (size_t)c * CIN + kc * 32 + ks * 8, lds_w + s * 8);
    }
    {
      const int s = t;
      const int n = s >> 2, ks = (s & 3) ^ (n & 3);
      gl_lds16(Xbf + (size_t)(g0 + n) * CIN + kc * 32 + ks * 8, lds_x + s * 8);
    }
    __syncthreads();

    bf16x8 af[4], bfr[4];
#pragma unroll
    for (int ct = 0; ct < 4; ++ct)
      af[ct] = *(const bf16x8*)(lds_w + (cw + ct * 16 + m) * 32 + xq * 8);
#pragma unroll
    for (int nt = 0; nt < 4; ++nt)
      bfr[nt] = *(const bf16x8*)(lds_x + (nt * 16 + m) * 32 + xq * 8);
#pragma unroll
    for (int ct = 0; ct < 4; ++ct)
#pragma unroll
      for (int nt = 0; nt < 4; ++nt)
        acc[ct][nt] = __builtin_amdgcn_mfma_f32_16x16x32_bf16(af[ct], bfr[nt], acc[ct][nt], 0, 0, 0);
  }

  u16* fragbase = fTf + (size_t)(((r * Bsz + b) * 4 + w) * 128) * 512;
#pragma unroll
  for (int ct = 0; ct < 4; ++ct) {
#pragma unroll
    for (int ntf = 0; ntf < 4; ++ntf) {
      const int j = n0 + ntf * 16 + m;
      const int jb = j >> 5;
      const int qt = ((ntf & 1) << 1) | (m >> 3);
      const int e = m & 7;
      u16* dst = fragbase + (size_t)((jb * 4 + ct) * 512) + (qt * 16 + quad * 4) * 8 + e;
#pragma unroll
      for (int p = 0; p < 4; ++p) dst[p * 8] = (u16)f2bf(acc[ct][ntf][p]);
    }
  }
}

// ---------- attention: factored-exp math + two-half LDS-staged EEj ----------
// grid 256: bid&7 = b (pins b's fTf/adjm to one XCD L2); bid>>3 = itile (32 i).
// block 1024 = 16 waves = (r = w&3, h = w>>2).
// exp(leaky(li+lj)) = max(e^li*e^lj, e^.2li*e^.2lj): per pr = 1 ds_read_b128
// (quad-uniform, 2-way alias = free) + 2 pk_mul + 2 fmax + 2 bfe + 2 and + 1 perm.
// EEj staged in LDS in TWO 64KB halves (j 0..511, then 512..1023) so static
// LDS stays at the in-session-proven 64KB (R3's 128KB static was the suspected
// container-kill). Epilogue: LDS r-reduction reusing the same buffer.
__global__ __launch_bounds__(1024, 4)
void gatt_attn(const unsigned long long* __restrict__ adjm,
               const u16* __restrict__ fTf, const float2* __restrict__ EEi,
               const float2* __restrict__ EEj, float* __restrict__ out) {
  __shared__ float smem[16384];  // 64KB: EEj half-staging; reused for epilogue tile

  const int t = threadIdx.x;
  const int b = blockIdx.x & 7;
  const int i0 = (blockIdx.x >> 3) * 32;
  const int w = t >> 6, lane = t & 63;
  const int r = w & 3, h = w >> 2;
  const int m = lane & 15, quad = lane >> 4;
  const int qo = quad * 8;
  const int combo = r * NH + h;

  const float2* EEib = EEi + ((size_t)(combo * Bsz + b)) * Nn;
  const float2 Li0 = EEib[i0 + m];
  const float2 Li1 = EEib[i0 + 16 + m];
  const f32x2 EI0 = {Li0.x, Li0.y};
  const f32x2 EI1 = {Li1.x, Li1.y};
  const float4* ej4 = (const float4*)(smem + combo * 1024);

  const unsigned long long* amp0 = adjm + ((size_t)((b * Nn + i0 + m) * NR + r)) * 16;
  const unsigned long long* amp1 = adjm + ((size_t)((b * Nn + i0 + 16 + m) * NR + r)) * 16;
  const bf16x8* fp = (const bf16x8*)fTf + (size_t)(((r * Bsz + b) * 4 + h)) * 8192;

  bf16x8 ones;
#pragma unroll
  for (int e = 0; e < 8; ++e) ones[e] = (short)0x3F80;

  f32x4 acc[2][4], den[2];
#pragma unroll
  for (int iw = 0; iw < 2; ++iw) {
    den[iw] = (f32x4){0.f, 0.f, 0.f, 0.f};
#pragma unroll
    for (int nt = 0; nt < 4; ++nt) acc[iw][nt] = (f32x4){0.f, 0.f, 0.f, 0.f};
  }

  for (int hs = 0; hs < 2; ++hs) {
    {  // stage EEj half hs: 16 combos x 512 j-entries (float2) = 64KB
#pragma unroll
      for (int q = 0; q < 4; ++q) {
        const int s = q * 1024 + t;       // s = cb*256 + off
        const int cb = s >> 8, off = s & 255;
        ((float4*)smem)[s] =
            ((const float4*)(EEj + ((size_t)(cb * Bsz + b)) * Nn))[hs * 256 + off];
      }
    }
    __syncthreads();

    for (int jq = hs * 8; jq < hs * 8 + 8; ++jq) {
      const uint2 mw0 = *(const uint2*)(amp0 + jq);
      const uint2 mw1 = *(const uint2*)(amp1 + jq);
#pragma unroll
      for (int half = 0; half < 2; ++half) {
        const int jb = jq * 2 + half;
        const int jbl = jb & 15;  // local jb within the staged half
        const unsigned mb0 = (half ? mw0.y : mw0.x) >> qo;
        const unsigned mb1 = (half ? mw1.y : mw1.x) >> qo;
        bf16x8 bfr[4];
#pragma unroll
        for (int nt = 0; nt < 4; ++nt) bfr[nt] = fp[(jb * 4 + nt) * 64 + lane];
        unsigned afu0[4], afu1[4];
#pragma unroll
        for (int pr = 0; pr < 4; ++pr) {
          const float4 v = ej4[jbl * 16 + quad * 4 + pr];  // {Ej0,ej0,Ej1,ej1}
          const f32x2 v01 = {v.x, v.y};
          const f32x2 v23 = {v.z, v.w};
          {  // iw 0
            const f32x2 a0 = v01 * EI0;  // {Ei*Ej0, ei*ej0}
            const f32x2 a1 = v23 * EI0;
            const unsigned e0 =
                __float_as_uint(fmaxf(a0.x, a0.y)) & (unsigned)sbfe1(mb0, 2 * pr);
            const unsigned e1 =
                __float_as_uint(fmaxf(a1.x, a1.y)) & (unsigned)sbfe1(mb0, 2 * pr + 1);
            afu0[pr] = perm_hi16(e1, e0);
          }
          {  // iw 1
            const f32x2 a0 = v01 * EI1;
            const f32x2 a1 = v23 * EI1;
            const unsigned e0 =
                __float_as_uint(fmaxf(a0.x, a0.y)) & (unsigned)sbfe1(mb1, 2 * pr);
            const unsigned e1 =
                __float_as_uint(fmaxf(a1.x, a1.y)) & (unsigned)sbfe1(mb1, 2 * pr + 1);
            afu1[pr] = perm_hi16(e1, e0);
          }
        }
        union { unsigned u[4]; bf16x8 v; } af0, af1;
#pragma unroll
        for (int pr = 0; pr < 4; ++pr) { af0.u[pr] = afu0[pr]; af1.u[pr] = afu1[pr]; }
        den[0] = __builtin_amdgcn_mfma_f32_16x16x32_bf16(af0.v, ones, den[0], 0, 0, 0);
#pragma unroll
        for (int nt = 0; nt < 4; ++nt)
          acc[0][nt] = __builtin_amdgcn_mfma_f32_16x16x32_bf16(af0.v, bfr[nt], acc[0][nt], 0, 0, 0);
        den[1] = __builtin_amdgcn_mfma_f32_16x16x32_bf16(af1.v, ones, den[1], 0, 0, 0);
#pragma unroll
        for (int nt = 0; nt < 4; ++nt)
          acc[1][nt] = __builtin_amdgcn_mfma_f32_16x16x32_bf16(af1.v, bfr[nt], acc[1][nt], 0, 0, 0);
      }
    }
    __syncthreads();  // before restaging / epilogue reuse
  }

  // ---- epilogue: r-reduction in LDS (smem reuse; loop ended with a barrier) ----
#define OSTRIDE 260
#pragma unroll
  for (int rr = 0; rr < 4; ++rr) {
    if (r == rr) {
#pragma unroll
      for (int iw = 0; iw < 2; ++iw) {
#pragma unroll
        for (int p = 0; p < 4; ++p) {
          const float inv = __builtin_amdgcn_rcpf(den[iw][p]);
          float* op = smem + (iw * 16 + quad * 4 + p) * OSTRIDE + h * 64 + m;
#pragma unroll
          for (int nt = 0; nt < 4; ++nt) {
            const float v = acc[iw][nt][p] * inv;
            if (rr == 0) op[nt * 16] = v;
            else op[nt * 16] += v;
          }
        }
      }
    }
    __syncthreads();
  }

  // ---- coalesced store of the 32x256 f32 tile ----
#pragma unroll
  for (int q = 0; q < 2; ++q) {
    const int idx = q * 1024 + t;
    const int row = idx >> 6, c4 = idx & 63;
    const float4 v = *(const float4*)(smem + row * OSTRIDE + c4 * 4);
    ((float4*)out)[((size_t)(b * Nn + i0 + row)) * 64 + c4] = v;
  }
}

extern "C" void kernel_launch(void* const* d_in, const int* in_sizes, int n_in,
                              void* d_out, int out_size, void* d_ws, size_t ws_size,
                              hipStream_t stream) {
  const float* X = (const float*)d_in[0];
  const int4* adj4 = (const int4*)d_in[1];
  const float* W = (const float*)d_in[2];
  const float* a = (const float*)d_in[3];
  float* out = (float*)d_out;

  char* ws = (char*)d_ws;
  u16* fTf = (u16*)ws;
  float2* EEi = (float2*)(ws + OFF_EEI);
  float2* EEj = (float2*)(ws + OFF_EEJ);
  unsigned long long* adjm = (unsigned long long*)(ws + OFF_ADJM);
  u16* Xbf = (u16*)(ws + OFF_XBF);
  u16* WbfT = (u16*)(ws + OFF_WBFT);
  float* wa_l = (float*)(ws + OFF_WAL);
  float* wa_r = (float*)(ws + OFF_WAR);

  gatt_pack<<<dim3(32768), dim3(256), 0, stream>>>(adj4, adjm);
  gatt_prep<<<dim3(48), dim3(256), 0, stream>>>(W, a, WbfT, wa_l, wa_r);
  gatt_logitx<<<dim3(512), dim3(256), 0, stream>>>(X, (const float4*)wa_l,
                                                   (const float4*)wa_r, EEi, EEj, Xbf);
  gatt_fgemm<<<dim3(512), dim3(256), 0, stream>>>(Xbf, WbfT, fTf);
  gatt_attn<<<dim3(256), dim3(1024), 0, stream>>>(adjm, fTf, EEi, EEj, out);
}

// Round 5
// 283.129 us; speedup vs baseline: 1.0762x; 1.0209x over previous
//
#include <hip/hip_runtime.h>
#include <math.h>

#define Bsz 8
#define Nn 1024
#define CIN 256
#define COUT 256
#define NR 4
#define NH 4

typedef unsigned short u16;
typedef __attribute__((ext_vector_type(8))) short bf16x8;
typedef __attribute__((ext_vector_type(4))) float f32x4;
typedef __attribute__((ext_vector_type(2))) float f32x2;

// ws layout (bytes):
//   fTf  : [sl=r*8+b][h][jb 0..31][nt 0..3][lane] bf16x8  16 MB @ 0
//   EEi  : [combo=r*4+h][b][n] float2 {e^li, e^(.2li)}    1 MB @ 16M
//   EEj  : [combo][b][n] float2 {e^lj, e^(.2lj)}          1 MB @ 17M
//   adjm : [b][i][r][16] u64                              4 MB @ 18M
//   Xbf  : [b*n][k] bf16                                  4 MB @ 22M
//   WbfT : [r][c][k] bf16                               512K @ 26M
//   wa_l : [combo][k] f32                                16K @ 26.5M
//   wa_r : [combo][k] f32                                16K @ +16K
#define OFF_EEI (16u << 20)
#define OFF_EEJ (17u << 20)
#define OFF_ADJM (18u << 20)
#define OFF_XBF (22u << 20)
#define OFF_WBFT (26u << 20)
#define OFF_WAL ((26u << 20) + (512u << 10))
#define OFF_WAR ((26u << 20) + (528u << 10))

#define LOG2E 1.4426950408889634f

// pack-block distribution across the three compute kernels (co-scheduling):
// prep' absorbs PK_PREP, logitx' absorbs PK_LGX, fgemm' the rest.
#define PK_PREP 3072
#define PK_LGX 6144
#define PK_TOTAL 32768

__device__ __forceinline__ short f2bf(float x) {
  union { float f; unsigned u; } v; v.f = x;
  unsigned r = (v.u + 0x7FFFu + ((v.u >> 16) & 1u)) >> 16;
  return (short)r;
}

__device__ __forceinline__ float fast_exp2(float x) {
#if __has_builtin(__builtin_amdgcn_exp2f)
  return __builtin_amdgcn_exp2f(x);
#else
  return exp2f(x);
#endif
}

__device__ __forceinline__ int sbfe1(unsigned v, int bit) {
#if __has_builtin(__builtin_amdgcn_sbfe)
  return __builtin_amdgcn_sbfe((int)v, bit, 1);
#else
  return ((int)(v << (31 - bit))) >> 31;
#endif
}

__device__ __forceinline__ unsigned perm_hi16(unsigned hi, unsigned lo) {
#if __has_builtin(__builtin_amdgcn_perm)
  return __builtin_amdgcn_perm(hi, lo, 0x07060302u);
#else
  return (lo >> 16) | (hi & 0xFFFF0000u);
#endif
}

// async global->LDS, 16B per lane
__device__ __forceinline__ void gl_lds16(const void* g, void* l) {
  __builtin_amdgcn_global_load_lds(
      (const __attribute__((address_space(1))) unsigned int*)(unsigned long long)g,
      (__attribute__((address_space(3))) unsigned int*)(unsigned int)(unsigned long long)l,
      16, 0, 0);
}

// ---------- adjacency pack (device body; blocks embedded in compute kernels) ----------
__device__ __forceinline__ void pack_body(int pbid, int t, const int4* __restrict__ adj4,
                                          unsigned long long* __restrict__ adjm) {
  const int wid = pbid * 4 + (t >> 6);
  const int lane = t & 63;
  const int jw = wid & 15;
  const int i = (wid >> 4) & 1023;
  const int b = wid >> 14;
  const int j = jw * 64 + lane;
  const int4 av = adj4[(size_t)(b * Nn + i) * Nn + j];
  const unsigned long long b0 = __ballot(av.x != 0);
  const unsigned long long b1 = __ballot(av.y != 0);
  const unsigned long long b2 = __ballot(av.z != 0);
  const unsigned long long b3 = __ballot(av.w != 0);
  if (lane < 4) {
    unsigned long long v = (lane == 0) ? b0 : (lane == 1) ? b1 : (lane == 2) ? b2 : b3;
    adjm[((size_t)((b * Nn + i) * NR + lane)) * 16 + jw] = v;
  }
}

// ---------- prep: W->bf16 transposed (bid<32) OR wa tables (bid 32..47) + pack blocks ----------
__global__ __launch_bounds__(256, 4)
void gatt_prep(const float* __restrict__ W, const float* __restrict__ a,
               u16* __restrict__ WbfT, float* __restrict__ wa_l,
               float* __restrict__ wa_r, const int4* __restrict__ adj4,
               unsigned long long* __restrict__ adjm) {
  const int t = threadIdx.x;
  if (blockIdx.x >= 48) {  // co-scheduled pack blocks [0, PK_PREP)
    pack_body(blockIdx.x - 48, t, adj4, adjm);
    return;
  }
  if (blockIdx.x < 32) {
    const int r = blockIdx.x >> 3, kc = blockIdx.x & 7;
    u16 pk[32];
#pragma unroll 8
    for (int kk = 0; kk < 32; ++kk)
      pk[kk] = (u16)f2bf(W[(size_t)r * 65536 + (size_t)(kc * 32 + kk) * COUT + t]);
    u16* dst = WbfT + (size_t)r * 65536 + (size_t)t * CIN + kc * 32;
#pragma unroll
    for (int q = 0; q < 4; ++q) *(int4*)(dst + q * 8) = *(int4*)(pk + q * 8);
  } else {
    const int cb = blockIdx.x - 32;
    const int r = cb >> 2, h = cb & 3;
    float sl = 0.f, sr = 0.f;
    const float* Wp = W + (size_t)r * 65536 + (size_t)t * COUT + h * 64;
    const float* ap = a + r * 512 + h * 128;
#pragma unroll 8
    for (int c = 0; c < 64; ++c) {
      const float wv = Wp[c];
      sl = fmaf(wv, ap[c], sl);
      sr = fmaf(wv, ap[64 + c], sr);
    }
    wa_l[(size_t)cb * CIN + t] = sl;
    wa_r[(size_t)cb * CIN + t] = sr;
  }
}

// ---------- logits -> factored exp tables {e^l, e^(0.2 l)} + X->bf16 + pack blocks ----------
__global__ __launch_bounds__(256, 4)
void gatt_logitx(const float* __restrict__ X, const float4* __restrict__ wal4,
                 const float4* __restrict__ war4, float2* __restrict__ EEi,
                 float2* __restrict__ EEj, u16* __restrict__ Xbf,
                 const int4* __restrict__ adj4, unsigned long long* __restrict__ adjm) {
  __shared__ float Xs[16 * 260];
  const int t = threadIdx.x;
  if (blockIdx.x >= 512) {  // co-scheduled pack blocks [PK_PREP, PK_PREP+PK_LGX)
    pack_body(blockIdx.x - 512 + PK_PREP, t, adj4, adjm);
    return;
  }
  const int row0 = blockIdx.x * 16;
  {
    const int il = t >> 4, kq = t & 15;
    const float4* xp = (const float4*)(X + (size_t)(row0 + il) * CIN + kq * 16);
    float4 v[4];
    u16 pk[16];
#pragma unroll
    for (int u = 0; u < 4; ++u) {
      v[u] = xp[u];
      pk[u * 4 + 0] = (u16)f2bf(v[u].x);
      pk[u * 4 + 1] = (u16)f2bf(v[u].y);
      pk[u * 4 + 2] = (u16)f2bf(v[u].z);
      pk[u * 4 + 3] = (u16)f2bf(v[u].w);
    }
    float4* dst = (float4*)(Xs + il * 260 + kq * 16);
#pragma unroll
    for (int u = 0; u < 4; ++u) dst[u] = v[u];
    u16* xb = Xbf + (size_t)(row0 + il) * CIN + kq * 16;
    *(int4*)xb = *(int4*)pk;
    *(int4*)(xb + 8) = *(int4*)(pk + 8);
  }
  __syncthreads();
  const int rl = t >> 4, combo = t & 15;
  float li = 0.f, lj = 0.f;
#pragma unroll 8
  for (int k4 = 0; k4 < 64; ++k4) {
    const float4 x4 = *(const float4*)(Xs + rl * 260 + k4 * 4);
    const float4 wl = wal4[combo * 64 + k4];
    const float4 wr = war4[combo * 64 + k4];
    li += x4.x * wl.x + x4.y * wl.y + x4.z * wl.z + x4.w * wl.w;
    lj += x4.x * wr.x + x4.y * wr.y + x4.z * wr.z + x4.w * wr.w;
  }
  const int g = row0 + rl, b = g >> 10, n = g & 1023;
  const size_t idx = ((size_t)(combo * Bsz + b)) * Nn + n;
  const float lis = li * LOG2E, ljs = lj * LOG2E;
  EEi[idx] = make_float2(fast_exp2(lis), fast_exp2(0.2f * lis));
  EEj[idx] = make_float2(fast_exp2(ljs), fast_exp2(0.2f * ljs));
}

// ---------- f GEMM via MFMA, frag-ordered output + pack blocks ----------
__global__ __launch_bounds__(256)
void gatt_fgemm(const u16* __restrict__ Xbf, const u16* __restrict__ WbfT,
                u16* __restrict__ fTf, const int4* __restrict__ adj4,
                unsigned long long* __restrict__ adjm) {
  __shared__ u16 lds_w[8192];
  __shared__ u16 lds_x[2048];
  const int t = threadIdx.x;
  if (blockIdx.x >= 512) {  // co-scheduled pack blocks [PK_PREP+PK_LGX, PK_TOTAL)
    pack_body(blockIdx.x - 512 + PK_PREP + PK_LGX, t, adj4, adjm);
    return;
  }
  const int r = blockIdx.x & 3, b = (blockIdx.x >> 2) & 7, ntl = blockIdx.x >> 5;
  const int n0 = ntl * 64;
  const int g0 = b * Nn + n0;
  const int lane = t & 63, w = t >> 6;
  const int m = lane & 15, quad = lane >> 4;
  const int cw = w * 64;
  const int xq = quad ^ (m & 3);

  const u16* Wsrc = WbfT + (size_t)r * 65536;
  f32x4 acc[4][4];
#pragma unroll
  for (int ct = 0; ct < 4; ++ct)
#pragma unroll
    for (int nt = 0; nt < 4; ++nt) acc[ct][nt] = (f32x4){0.f, 0.f, 0.f, 0.f};

  for (int kc = 0; kc < 8; ++kc) {
    __syncthreads();
#pragma unroll
    for (int q = 0; q < 4; ++q) {
      const int s = q * 256 + t;
      const int c = s >> 2, ks = (s & 3) ^ (c & 3);
      gl_lds16(Wsrc + (size_t)c * CIN + kc * 32 + ks * 8, lds_w + s * 8);
    }
    {
      const int s = t;
      const int n = s >> 2, ks = (s & 3) ^ (n & 3);
      gl_lds16(Xbf + (size_t)(g0 + n) * CIN + kc * 32 + ks * 8, lds_x + s * 8);
    }
    __syncthreads();

    bf16x8 af[4], bfr[4];
#pragma unroll
    for (int ct = 0; ct < 4; ++ct)
      af[ct] = *(const bf16x8*)(lds_w + (cw + ct * 16 + m) * 32 + xq * 8);
#pragma unroll
    for (int nt = 0; nt < 4; ++nt)
      bfr[nt] = *(const bf16x8*)(lds_x + (nt * 16 + m) * 32 + xq * 8);
#pragma unroll
    for (int ct = 0; ct < 4; ++ct)
#pragma unroll
      for (int nt = 0; nt < 4; ++nt)
        acc[ct][nt] = __builtin_amdgcn_mfma_f32_16x16x32_bf16(af[ct], bfr[nt], acc[ct][nt], 0, 0, 0);
  }

  u16* fragbase = fTf + (size_t)(((r * Bsz + b) * 4 + w) * 128) * 512;
#pragma unroll
  for (int ct = 0; ct < 4; ++ct) {
#pragma unroll
    for (int ntf = 0; ntf < 4; ++ntf) {
      const int j = n0 + ntf * 16 + m;
      const int jb = j >> 5;
      const int qt = ((ntf & 1) << 1) | (m >> 3);
      const int e = m & 7;
      u16* dst = fragbase + (size_t)((jb * 4 + ct) * 512) + (qt * 16 + quad * 4) * 8 + e;
#pragma unroll
      for (int p = 0; p < 4; ++p) dst[p * 8] = (u16)f2bf(acc[ct][ntf][p]);
    }
  }
}

// ---------- attention: factored-exp math + two-half LDS-staged EEj (unchanged R4) ----------
__global__ __launch_bounds__(1024, 4)
void gatt_attn(const unsigned long long* __restrict__ adjm,
               const u16* __restrict__ fTf, const float2* __restrict__ EEi,
               const float2* __restrict__ EEj, float* __restrict__ out) {
  __shared__ float smem[16384];  // 64KB: EEj half-staging; reused for epilogue tile

  const int t = threadIdx.x;
  const int b = blockIdx.x & 7;
  const int i0 = (blockIdx.x >> 3) * 32;
  const int w = t >> 6, lane = t & 63;
  const int r = w & 3, h = w >> 2;
  const int m = lane & 15, quad = lane >> 4;
  const int qo = quad * 8;
  const int combo = r * NH + h;

  const float2* EEib = EEi + ((size_t)(combo * Bsz + b)) * Nn;
  const float2 Li0 = EEib[i0 + m];
  const float2 Li1 = EEib[i0 + 16 + m];
  const f32x2 EI0 = {Li0.x, Li0.y};
  const f32x2 EI1 = {Li1.x, Li1.y};
  const float4* ej4 = (const float4*)(smem + combo * 1024);

  const unsigned long long* amp0 = adjm + ((size_t)((b * Nn + i0 + m) * NR + r)) * 16;
  const unsigned long long* amp1 = adjm + ((size_t)((b * Nn + i0 + 16 + m) * NR + r)) * 16;
  const bf16x8* fp = (const bf16x8*)fTf + (size_t)(((r * Bsz + b) * 4 + h)) * 8192;

  bf16x8 ones;
#pragma unroll
  for (int e = 0; e < 8; ++e) ones[e] = (short)0x3F80;

  f32x4 acc[2][4], den[2];
#pragma unroll
  for (int iw = 0; iw < 2; ++iw) {
    den[iw] = (f32x4){0.f, 0.f, 0.f, 0.f};
#pragma unroll
    for (int nt = 0; nt < 4; ++nt) acc[iw][nt] = (f32x4){0.f, 0.f, 0.f, 0.f};
  }

  for (int hs = 0; hs < 2; ++hs) {
    {  // stage EEj half hs: 16 combos x 512 j-entries (float2) = 64KB
#pragma unroll
      for (int q = 0; q < 4; ++q) {
        const int s = q * 1024 + t;       // s = cb*256 + off
        const int cb = s >> 8, off = s & 255;
        ((float4*)smem)[s] =
            ((const float4*)(EEj + ((size_t)(cb * Bsz + b)) * Nn))[hs * 256 + off];
      }
    }
    __syncthreads();

    for (int jq = hs * 8; jq < hs * 8 + 8; ++jq) {
      const uint2 mw0 = *(const uint2*)(amp0 + jq);
      const uint2 mw1 = *(const uint2*)(amp1 + jq);
#pragma unroll
      for (int half = 0; half < 2; ++half) {
        const int jb = jq * 2 + half;
        const int jbl = jb & 15;  // local jb within the staged half
        const unsigned mb0 = (half ? mw0.y : mw0.x) >> qo;
        const unsigned mb1 = (half ? mw1.y : mw1.x) >> qo;
        bf16x8 bfr[4];
#pragma unroll
        for (int nt = 0; nt < 4; ++nt) bfr[nt] = fp[(jb * 4 + nt) * 64 + lane];
        unsigned afu0[4], afu1[4];
#pragma unroll
        for (int pr = 0; pr < 4; ++pr) {
          const float4 v = ej4[jbl * 16 + quad * 4 + pr];  // {Ej0,ej0,Ej1,ej1}
          const f32x2 v01 = {v.x, v.y};
          const f32x2 v23 = {v.z, v.w};
          {  // iw 0
            const f32x2 a0 = v01 * EI0;  // {Ei*Ej0, ei*ej0}
            const f32x2 a1 = v23 * EI0;
            const unsigned e0 =
                __float_as_uint(fmaxf(a0.x, a0.y)) & (unsigned)sbfe1(mb0, 2 * pr);
            const unsigned e1 =
                __float_as_uint(fmaxf(a1.x, a1.y)) & (unsigned)sbfe1(mb0, 2 * pr + 1);
            afu0[pr] = perm_hi16(e1, e0);
          }
          {  // iw 1
            const f32x2 a0 = v01 * EI1;
            const f32x2 a1 = v23 * EI1;
            const unsigned e0 =
                __float_as_uint(fmaxf(a0.x, a0.y)) & (unsigned)sbfe1(mb1, 2 * pr);
            const unsigned e1 =
                __float_as_uint(fmaxf(a1.x, a1.y)) & (unsigned)sbfe1(mb1, 2 * pr + 1);
            afu1[pr] = perm_hi16(e1, e0);
          }
        }
        union { unsigned u[4]; bf16x8 v; } af0, af1;
#pragma unroll
        for (int pr = 0; pr < 4; ++pr) { af0.u[pr] = afu0[pr]; af1.u[pr] = afu1[pr]; }
        den[0] = __builtin_amdgcn_mfma_f32_16x16x32_bf16(af0.v, ones, den[0], 0, 0, 0);
#pragma unroll
        for (int nt = 0; nt < 4; ++nt)
          acc[0][nt] = __builtin_amdgcn_mfma_f32_16x16x32_bf16(af0.v, bfr[nt], acc[0][nt], 0, 0, 0);
        den[1] = __builtin_amdgcn_mfma_f32_16x16x32_bf16(af1.v, ones, den[1], 0, 0, 0);
#pragma unroll
        for (int nt = 0; nt < 4; ++nt)
          acc[1][nt] = __builtin_amdgcn_mfma_f32_16x16x32_bf16(af1.v, bfr[nt], acc[1][nt], 0, 0, 0);
      }
    }
    __syncthreads();  // before restaging / epilogue reuse
  }

  // ---- epilogue: r-reduction in LDS (smem reuse; loop ended with a barrier) ----
#define OSTRIDE 260
#pragma unroll
  for (int rr = 0; rr < 4; ++rr) {
    if (r == rr) {
#pragma unroll
      for (int iw = 0; iw < 2; ++iw) {
#pragma unroll
        for (int p = 0; p < 4; ++p) {
          const float inv = __builtin_amdgcn_rcpf(den[iw][p]);
          float* op = smem + (iw * 16 + quad * 4 + p) * OSTRIDE + h * 64 + m;
#pragma unroll
          for (int nt = 0; nt < 4; ++nt) {
            const float v = acc[iw][nt][p] * inv;
            if (rr == 0) op[nt * 16] = v;
            else op[nt * 16] += v;
          }
        }
      }
    }
    __syncthreads();
  }

  // ---- coalesced store of the 32x256 f32 tile ----
#pragma unroll
  for (int q = 0; q < 2; ++q) {
    const int idx = q * 1024 + t;
    const int row = idx >> 6, c4 = idx & 63;
    const float4 v = *(const float4*)(smem + row * OSTRIDE + c4 * 4);
    ((float4*)out)[((size_t)(b * Nn + i0 + row)) * 64 + c4] = v;
  }
}

extern "C" void kernel_launch(void* const* d_in, const int* in_sizes, int n_in,
                              void* d_out, int out_size, void* d_ws, size_t ws_size,
                              hipStream_t stream) {
  const float* X = (const float*)d_in[0];
  const int4* adj4 = (const int4*)d_in[1];
  const float* W = (const float*)d_in[2];
  const float* a = (const float*)d_in[3];
  float* out = (float*)d_out;

  char* ws = (char*)d_ws;
  u16* fTf = (u16*)ws;
  float2* EEi = (float2*)(ws + OFF_EEI);
  float2* EEj = (float2*)(ws + OFF_EEJ);
  unsigned long long* adjm = (unsigned long long*)(ws + OFF_ADJM);
  u16* Xbf = (u16*)(ws + OFF_XBF);
  u16* WbfT = (u16*)(ws + OFF_WBFT);
  float* wa_l = (float*)(ws + OFF_WAL);
  float* wa_r = (float*)(ws + OFF_WAR);

  // pack's 32768 blocks are distributed across the three compute kernels:
  // each kernel's BW-idle time absorbs pack's HBM-bound adjacency read.
  gatt_prep<<<dim3(48 + PK_PREP), dim3(256), 0, stream>>>(W, a, WbfT, wa_l, wa_r,
                                                          adj4, adjm);
  gatt_logitx<<<dim3(512 + PK_LGX), dim3(256), 0, stream>>>(
      X, (const float4*)wa_l, (const float4*)wa_r, EEi, EEj, Xbf, adj4, adjm);
  gatt_fgemm<<<dim3(512 + (PK_TOTAL - PK_PREP - PK_LGX)), dim3(256), 0, stream>>>(
      Xbf, WbfT, fTf, adj4, adjm);
  gatt_attn<<<dim3(256), dim3(1024), 0, stream>>>(adjm, fTf, EEi, EEj, out);
}